// Round 24
// baseline (176.126 us; speedup 1.0000x reference)
//
#include <hip/hip_runtime.h>
#include <hip/hip_bf16.h>
#include <math.h>

// B=8, N=1024, DIM=1024, H=16, D_K=64
// Pipeline (all-fp16 MFMA, fp32 accum):
//   merged cast kernel: x -> fp16; w_qkv, w_out -> fp16 transposed [col][k]
//   GEMM1 (BK=64, 128x128 tile, 32x32x16 MFMA): qk[8192][2048] (Q
//     pre-scaled by 0.125*log2e) and V transposed into vT[(b,h)][64][1024].
//     32x32x16 halves MFMA instruction count vs 16x16x32 (higher ceiling,
//     2178 vs 1955 TF); operand/D layouts identical to the ones verified
//     in the attention kernel (A row=lane&31, k=(lane>>5)*8+e; D row=
//     (reg&3)+8*(reg>>2)+4*hi, col=lane&31).
//   flash attention (R21): NO-MAX softmax, MFMA-l, counted-vmcnt 3-buffer.
//   GEMM2 (BK=64, 32x32x16): out = attn @ woT + b_out -> fp32
//
// ws layout (96 MiB):
//   [0,16Mi)   xh [8192][1024] f16   (later reused as attn output plane)
//   [32,38Mi)  wqT [3072][1024] f16
//   [44,46Mi)  woT [1024][1024] f16
//   [48,80Mi)  qk f16 [8192][2048]
//   [80,96Mi)  vT f16 [8*16][64][1024]

typedef __attribute__((ext_vector_type(8))) _Float16 f16x8;
typedef __attribute__((ext_vector_type(4))) _Float16 f16x4;
typedef __attribute__((ext_vector_type(4))) float f32x4;
typedef __attribute__((ext_vector_type(16))) float f32x16;
typedef __attribute__((ext_vector_type(4))) unsigned int u32x4;

#define QK_SCALE 0.18033688011112042f   // 0.125 * log2(e)

#define GLOBAL_LOAD_LDS16(g, l) \
  __builtin_amdgcn_global_load_lds((const __attribute__((address_space(1))) void*)(g), \
                                   (__attribute__((address_space(3))) void*)(l), 16, 0, 0)

// ---------- merged casts: x->fp16 ; w_qkv, w_out -> fp16 transposed ----------
__global__ __launch_bounds__(256) void cast_all(
    const float* __restrict__ x, _Float16* __restrict__ xh,
    const float* __restrict__ w_qkv, _Float16* __restrict__ wqT,
    const float* __restrict__ w_out, _Float16* __restrict__ woT) {
  __shared__ _Float16 hs[64][65];
  const int blk = blockIdx.x;
  const int t = threadIdx.x;

  if (blk < 2048) {
    const int n4 = 8192 * 1024 / 4;
    int i = blk * 256 + t;
    const int stride = 2048 * 256;
    for (; i < n4; i += stride) {
      float4 v = ((const float4*)x)[i];
      f16x4 h;
      h[0] = (_Float16)v.x; h[1] = (_Float16)v.y;
      h[2] = (_Float16)v.z; h[3] = (_Float16)v.w;
      ((f16x4*)xh)[i] = h;
    }
    return;
  }

  const float* in;
  _Float16* hi;
  int R, C, bx, by;
  if (blk < 2048 + 768) {
    const int id = blk - 2048;
    in = w_qkv; hi = wqT; R = 1024; C = 3072;
    bx = id % 48; by = id / 48;
  } else {
    const int id = blk - 2816;
    in = w_out; hi = woT; R = 1024; C = 1024;
    bx = id % 16; by = id / 16;
  }
  const int r0 = by * 64, c0 = bx * 64;
#pragma unroll
  for (int it = 0; it < 4; ++it) {
    int r = (t >> 4) + it * 16;
    int cc = (t & 15) * 4;
    float4 v = *(const float4*)(in + (size_t)(r0 + r) * C + c0 + cc);
    hs[r][cc + 0] = (_Float16)v.x;
    hs[r][cc + 1] = (_Float16)v.y;
    hs[r][cc + 2] = (_Float16)v.z;
    hs[r][cc + 3] = (_Float16)v.w;
  }
  __syncthreads();
  const int oc = t >> 2;
  const int rr = (t & 3) * 16;
#pragma unroll
  for (int g = 0; g < 2; ++g) {
    f16x8 a;
#pragma unroll
    for (int j = 0; j < 8; ++j) a[j] = hs[rr + g * 8 + j][oc];
    *(f16x8*)(hi + (size_t)(c0 + oc) * R + r0 + rr + g * 8) = a;
  }
}

// ---------- GEMM1: qkv = xh @ wqT, 128x128 tile, BK=64, 32x32x16 ----------
__global__ __launch_bounds__(256) void gemm1_qkv(
    const _Float16* __restrict__ Ah, const _Float16* __restrict__ Bh,
    _Float16* __restrict__ qkout, _Float16* __restrict__ vTout) {
  __shared__ char lds[34816];   // staging 2*16384=32768; epilogue 34816
  const int K = 1024;
  const int tid = threadIdx.x;
  const int wave = tid >> 6, lane = tid & 63;
  const int m0 = blockIdx.y * 128, n0 = blockIdx.x * 128;
  const int wr = wave >> 1, wc = wave & 1;
  const int l31 = lane & 31, hi = lane >> 5;

  const int srow_off = lane >> 3;   // 0..7
  const int slot     = lane & 7;

  f32x16 acc[2][2];
#pragma unroll
  for (int mi = 0; mi < 2; ++mi)
#pragma unroll
    for (int ni = 0; ni < 2; ++ni) acc[mi][ni] = (f32x16){0};

  const _Float16* gbase[2];
  gbase[0] = Ah + (size_t)m0 * K;
  gbase[1] = Bh + (size_t)n0 * K;

  for (int k0 = 0; k0 < K; k0 += 64) {
    __syncthreads();
#pragma unroll
    for (int p = 0; p < 2; ++p) {
#pragma unroll
      for (int it = 0; it < 4; ++it) {
        const int rbase = wave * 32 + it * 8;
        const int r  = rbase + srow_off;
        const int gc = slot ^ (r & 7);
        const _Float16* g = gbase[p] + (size_t)r * K + k0 + gc * 8;
        GLOBAL_LOAD_LDS16(g, lds + p * 16384 + rbase * 128);
      }
    }
    __syncthreads();

#pragma unroll
    for (int ks = 0; ks < 4; ++ks) {
      f16x8 af[2], bf[2];
#pragma unroll
      for (int mi = 0; mi < 2; ++mi) {
        const int r = wr * 64 + mi * 32 + l31;
        af[mi] = *(const f16x8*)(lds + 0 * 16384 + r * 128 +
                                 (((2 * ks + hi) ^ (r & 7)) * 16));
      }
#pragma unroll
      for (int ni = 0; ni < 2; ++ni) {
        const int r = wc * 64 + ni * 32 + l31;
        bf[ni] = *(const f16x8*)(lds + 1 * 16384 + r * 128 +
                                 (((2 * ks + hi) ^ (r & 7)) * 16));
      }
#pragma unroll
      for (int mi = 0; mi < 2; ++mi)
#pragma unroll
        for (int ni = 0; ni < 2; ++ni)
          acc[mi][ni] = __builtin_amdgcn_mfma_f32_32x32x16_f16(
              af[mi], bf[ni], acc[mi][ni], 0, 0, 0);
    }
  }

  // epilogue: D row = (reg&3)+8*(reg>>2)+4*hi, col = lane&31 (verified map)
  if (n0 < 2048) {
    const float qsc = (n0 < 1024) ? (float)QK_SCALE : 1.0f;
#pragma unroll
    for (int mi = 0; mi < 2; ++mi)
#pragma unroll
      for (int ni = 0; ni < 2; ++ni) {
        const int col = n0 + wc * 64 + ni * 32 + l31;
#pragma unroll
        for (int reg = 0; reg < 16; ++reg) {
          const int row = m0 + wr * 64 + mi * 32 + (reg & 3) + 8 * (reg >> 2) + 4 * hi;
          qkout[(size_t)row * 2048 + col] = (_Float16)(acc[mi][ni][reg] * qsc);
        }
      }
  } else {
    __syncthreads();
    _Float16* lv = (_Float16*)lds;        // [128 cols][136]
#pragma unroll
    for (int mi = 0; mi < 2; ++mi)
#pragma unroll
      for (int ni = 0; ni < 2; ++ni) {
        const int cc = wc * 64 + ni * 32 + l31;
#pragma unroll
        for (int reg = 0; reg < 16; ++reg) {
          const int r = wr * 64 + mi * 32 + (reg & 3) + 8 * (reg >> 2) + 4 * hi;
          lv[cc * 136 + r] = (_Float16)acc[mi][ni][reg];
        }
      }
    __syncthreads();
    const int bb = m0 >> 10, seq0 = m0 & 1023;
    const int hbase = (n0 - 2048) >> 6;
#pragma unroll
    for (int it = 0; it < 8; ++it) {
      const int idx = tid + it * 256;
      const int cc = idx >> 4, ch = idx & 15;
      f16x8 v = *(const f16x8*)(lv + cc * 136 + ch * 8);
      const int hh = hbase + (cc >> 6), d = cc & 63;
      *(f16x8*)(vTout + (((size_t)bb * 16 + hh) * 64 + d) * 1024 + seq0 + ch * 8) = v;
    }
  }
}

// ---------- MFMA flash attention (counted-vmcnt pipeline) ----------
// grid (128, 8): x = h*8+b (XCD-local K/V), y = band. Block = 4 waves;
// wave owns 32 q-rows; KVBLK=64; THREE LDS buffers, depth-2 prefetch.
__global__ __launch_bounds__(256) void attn_mfma(
    const _Float16* __restrict__ qk,   // [8192][2048]
    const _Float16* __restrict__ vT,   // [(b*16+h)*64 + dim][1024]
    _Float16* __restrict__ ao) {       // [8192][1024]
  const int hb   = blockIdx.x;
  const int h    = hb >> 3;
  const int b    = hb & 7;
  const int band = blockIdx.y;
  const int tid  = threadIdx.x;
  const int wave = tid >> 6;
  const int lane = tid & 63;
  const int l31  = lane & 31;
  const int hi   = lane >> 5;
  const int kswz = (l31 & 7) << 4;

  __shared__ _Float16 Ks[3][64 * 64];
  __shared__ _Float16 Vt[3][64 * 64];

  const _Float16* vbase = vT + ((size_t)(b * 16 + h) * 64) * 1024;

  const int qrow_g = b * 1024 + band * 128 + wave * 32 + l31;
  f16x8 qf[4];
#pragma unroll
  for (int c = 0; c < 4; ++c)
    qf[c] = *(const f16x8*)(qk + (size_t)qrow_g * 2048 + h * 64 + c * 16 + hi * 8);

  f16x8 vones;
#pragma unroll
  for (int j = 0; j < 8; ++j) vones[j] = (_Float16)1.0f;

  f32x16 accO0 = {0}, accO1 = {0}, accL = {0};

  const int srow8 = (lane >> 3);
  const int slot  = lane & 7;

  auto stage_t = [&](int t, int buf) {
#pragma unroll
    for (int it = 0; it < 2; ++it) {
      const int r  = wave * 8 + srow8 + it * 32;
      const int gc = slot ^ (r & 7);
      const _Float16* gk = qk + (size_t)(b * 1024 + t * 64 + r) * 2048 +
                           1024 + h * 64 + gc * 8;
      const _Float16* gv = vbase + (size_t)r * 1024 + t * 64 + gc * 8;
      char* dk = (char*)&Ks[buf][0] + (wave * 8 + it * 32) * 128;
      char* dv = (char*)&Vt[buf][0] + (wave * 8 + it * 32) * 128;
      GLOBAL_LOAD_LDS16(gk, dk);
      GLOBAL_LOAD_LDS16(gv, dv);
    }
  };

  auto compute_tile = [&](const char* ksb, const char* vtb) {
    f32x16 accS0 = {0}, accS1 = {0};
    __builtin_amdgcn_s_setprio(1);
#pragma unroll
    for (int c = 0; c < 4; ++c) {
      f16x8 ka0 = *(const f16x8*)(ksb + l31 * 128 + ((c * 32 + hi * 16) ^ kswz));
      f16x8 ka1 = *(const f16x8*)(ksb + (l31 + 32) * 128 + ((c * 32 + hi * 16) ^ kswz));
      accS0 = __builtin_amdgcn_mfma_f32_32x32x16_f16(ka0, qf[c], accS0, 0, 0, 0);
      accS1 = __builtin_amdgcn_mfma_f32_32x32x16_f16(ka1, qf[c], accS1, 0, 0, 0);
    }
    __builtin_amdgcn_s_setprio(0);

#pragma unroll
    for (int c = 0; c < 4; ++c) {
      float e[8];
#pragma unroll
      for (int k = 0; k < 8; ++k)
        e[k] = __builtin_exp2f((c < 2) ? accS0[(c & 1) * 8 + k]
                                       : accS1[(c & 1) * 8 + k]);
      unsigned q0a = __builtin_bit_cast(unsigned, __builtin_amdgcn_cvt_pkrtz(e[0], e[1]));
      unsigned q0b = __builtin_bit_cast(unsigned, __builtin_amdgcn_cvt_pkrtz(e[2], e[3]));
      unsigned q1a = __builtin_bit_cast(unsigned, __builtin_amdgcn_cvt_pkrtz(e[4], e[5]));
      unsigned q1b = __builtin_bit_cast(unsigned, __builtin_amdgcn_cvt_pkrtz(e[6], e[7]));
      unsigned send_a = hi ? q0a : q1a;
      unsigned send_b = hi ? q0b : q1b;
      unsigned recv_a = __shfl_xor(send_a, 32);
      unsigned recv_b = __shfl_xor(send_b, 32);
      u32x4 pu;
      pu[0] = hi ? recv_a : q0a;
      pu[1] = hi ? recv_b : q0b;
      pu[2] = hi ? q1a : recv_a;
      pu[3] = hi ? q1b : recv_b;
      f16x8 pa = __builtin_bit_cast(f16x8, pu);

      const int kchunk = ((2 * c + hi) * 16) ^ kswz;
      f16x8 vb0 = *(const f16x8*)(vtb + l31 * 128 + kchunk);
      f16x8 vb1 = *(const f16x8*)(vtb + (l31 + 32) * 128 + kchunk);
      __builtin_amdgcn_s_setprio(1);
      accO0 = __builtin_amdgcn_mfma_f32_32x32x16_f16(pa, vb0, accO0, 0, 0, 0);
      accO1 = __builtin_amdgcn_mfma_f32_32x32x16_f16(pa, vb1, accO1, 0, 0, 0);
      accL  = __builtin_amdgcn_mfma_f32_32x32x16_f16(pa, vones, accL, 0, 0, 0);
      __builtin_amdgcn_s_setprio(0);
    }
  };

  stage_t(0, 0);
  stage_t(1, 1);

  for (int t = 0; t < 14; ++t) {
    __builtin_amdgcn_s_barrier();                    // A: all done compute(t-1)
    stage_t(t + 2, (t + 2) % 3);                     // overwrite buf[(t-1)%3]
    asm volatile("s_waitcnt vmcnt(8)" ::: "memory"); // drain exactly stage(t)
    __builtin_amdgcn_sched_barrier(0);
    __builtin_amdgcn_s_barrier();                    // B: everyone's stage(t) landed
    const int bt = t % 3;
    compute_tile((const char*)&Ks[bt][0], (const char*)&Vt[bt][0]);
  }
  asm volatile("s_waitcnt vmcnt(4)" ::: "memory");
  __builtin_amdgcn_sched_barrier(0);
  __builtin_amdgcn_s_barrier();
  compute_tile((const char*)&Ks[2][0], (const char*)&Vt[2][0]);   // 14%3=2
  asm volatile("s_waitcnt vmcnt(0)" ::: "memory");
  __builtin_amdgcn_sched_barrier(0);
  __builtin_amdgcn_s_barrier();
  compute_tile((const char*)&Ks[0][0], (const char*)&Vt[0][0]);   // 15%3=0

#pragma unroll
  for (int reg = 0; reg < 16; ++reg) {
    const int qr = (reg & 3) + 8 * (reg >> 2) + 4 * hi;
    const float il = 1.f / accL[reg];
    const size_t grow = (size_t)(b * 1024 + band * 128 + wave * 32 + qr) * 1024 + h * 64;
    ao[grow + l31]      = (_Float16)(accO0[reg] * il);
    ao[grow + 32 + l31] = (_Float16)(accO1[reg] * il);
  }
}

// ---------- GEMM2: out = attn @ woT + bias, BK=64, 32x32x16 ----------
__global__ __launch_bounds__(256) void gemm2_out(
    const _Float16* __restrict__ A,
    const _Float16* __restrict__ B,
    float* __restrict__ C, const float* __restrict__ bias) {
  __shared__ char lds[2 * 16384];
  const int K = 1024;
  const int tid = threadIdx.x;
  const int wave = tid >> 6, lane = tid & 63;
  const int m0 = blockIdx.y * 128, n0 = blockIdx.x * 128;
  const int wr = wave >> 1, wc = wave & 1;
  const int l31 = lane & 31, hi = lane >> 5;

  const int srow_off = lane >> 3;
  const int slot     = lane & 7;

  f32x16 acc[2][2];
#pragma unroll
  for (int mi = 0; mi < 2; ++mi)
#pragma unroll
    for (int ni = 0; ni < 2; ++ni) acc[mi][ni] = (f32x16){0};

  const _Float16* gbase[2];
  gbase[0] = A + (size_t)m0 * K;
  gbase[1] = B + (size_t)n0 * K;

  for (int k0 = 0; k0 < K; k0 += 64) {
    __syncthreads();
#pragma unroll
    for (int p = 0; p < 2; ++p) {
#pragma unroll
      for (int it = 0; it < 4; ++it) {
        const int rbase = wave * 32 + it * 8;
        const int r  = rbase + srow_off;
        const int gc = slot ^ (r & 7);
        const _Float16* g = gbase[p] + (size_t)r * K + k0 + gc * 8;
        GLOBAL_LOAD_LDS16(g, lds + p * 16384 + rbase * 128);
      }
    }
    __syncthreads();

#pragma unroll
    for (int ks = 0; ks < 4; ++ks) {
      f16x8 af[2], bf[2];
#pragma unroll
      for (int mi = 0; mi < 2; ++mi) {
        const int r = wr * 64 + mi * 32 + l31;
        af[mi] = *(const f16x8*)(lds + 0 * 16384 + r * 128 +
                                 (((2 * ks + hi) ^ (r & 7)) * 16));
      }
#pragma unroll
      for (int ni = 0; ni < 2; ++ni) {
        const int r = wc * 64 + ni * 32 + l31;
        bf[ni] = *(const f16x8*)(lds + 1 * 16384 + r * 128 +
                                 (((2 * ks + hi) ^ (r & 7)) * 16));
      }
#pragma unroll
      for (int mi = 0; mi < 2; ++mi)
#pragma unroll
        for (int ni = 0; ni < 2; ++ni)
          acc[mi][ni] = __builtin_amdgcn_mfma_f32_32x32x16_f16(
              af[mi], bf[ni], acc[mi][ni], 0, 0, 0);
    }
  }

#pragma unroll
  for (int mi = 0; mi < 2; ++mi)
#pragma unroll
    for (int ni = 0; ni < 2; ++ni) {
      const int col = n0 + wc * 64 + ni * 32 + l31;
      const float bv = bias[col];
#pragma unroll
      for (int reg = 0; reg < 16; ++reg) {
        const int row = m0 + wr * 64 + mi * 32 + (reg & 3) + 8 * (reg >> 2) + 4 * hi;
        C[(size_t)row * 1024 + col] = acc[mi][ni][reg] + bv;
      }
    }
}

extern "C" void kernel_launch(void* const* d_in, const int* in_sizes, int n_in,
                              void* d_out, int out_size, void* d_ws, size_t ws_size,
                              hipStream_t stream) {
  const float* x     = (const float*)d_in[0];   // [8, 1024, 1024]
  const float* w_qkv = (const float*)d_in[1];   // [1024, 3072]
  const float* w_out = (const float*)d_in[2];   // [1024, 1024]
  const float* b_out = (const float*)d_in[3];   // [1024]
  float* out = (float*)d_out;                   // [8, 1024, 1024]

  char* ws = (char*)d_ws;
  _Float16* xh  = (_Float16*)(ws);
  _Float16* ao  = xh;                           // reused after GEMM1
  _Float16* wqT = (_Float16*)(ws + (32u << 20));
  _Float16* woT = (_Float16*)(ws + (44u << 20));
  _Float16* qkp = (_Float16*)(ws + (48u << 20));
  _Float16* vT  = (_Float16*)(ws + (80u << 20));

  // merged casts (x, w_qkv^T, w_out^T) in one launch
  cast_all<<<3072, 256, 0, stream>>>(x, xh, w_qkv, wqT, w_out, woT);

  // qkv = xh @ wqT  (M=8192, N=3072, K=1024); Q pre-scaled
  gemm1_qkv<<<dim3(24, 64), 256, 0, stream>>>(xh, wqT, qkp, vT);

  // attention: grid x=(h,b) so bands sharing K/V stay on one XCD
  attn_mfma<<<dim3(128, 8), 256, 0, stream>>>(qkp, vT, ao);

  // out = attn @ w_out + b_out (M=8192, N=1024, K=1024) -> f32
  gemm2_out<<<dim3(8, 64), 256, 0, stream>>>(ao, woT, out, b_out);
}

// Round 25
// 172.340 us; speedup vs baseline: 1.0220x; 1.0220x over previous
//
#include <hip/hip_runtime.h>
#include <hip/hip_bf16.h>
#include <math.h>

// B=8, N=1024, DIM=1024, H=16, D_K=64
// Pipeline (all-fp16 MFMA, fp32 accum):
//   merged cast kernel: x -> fp16; w_qkv, w_out -> fp16 transposed [col][k]
//   GEMM1 (BK=64, 128x128 tile, 32x32x16 MFMA): qk[8192][2048] (Q
//     pre-scaled by 0.125*log2e) and V transposed into vT[(b,h)][64][1024].
//   flash attention (R21 + FULL UNROLL): NO-MAX softmax, MFMA-l,
//     counted-vmcnt 3-buffer pipeline. Main t-loop fully unrolled so
//     t%3 / staged addresses / buffer bases fold to compile-time consts
//     (dynamic-loop address recompute was inflating VALUBusy to 57%).
//   GEMM2 (BK=64, 32x32x16): out = attn @ woT + b_out -> fp32
//
// ws layout (96 MiB):
//   [0,16Mi)   xh [8192][1024] f16   (later reused as attn output plane)
//   [32,38Mi)  wqT [3072][1024] f16
//   [44,46Mi)  woT [1024][1024] f16
//   [48,80Mi)  qk f16 [8192][2048]
//   [80,96Mi)  vT f16 [8*16][64][1024]

typedef __attribute__((ext_vector_type(8))) _Float16 f16x8;
typedef __attribute__((ext_vector_type(4))) _Float16 f16x4;
typedef __attribute__((ext_vector_type(4))) float f32x4;
typedef __attribute__((ext_vector_type(16))) float f32x16;
typedef __attribute__((ext_vector_type(4))) unsigned int u32x4;

#define QK_SCALE 0.18033688011112042f   // 0.125 * log2(e)

#define GLOBAL_LOAD_LDS16(g, l) \
  __builtin_amdgcn_global_load_lds((const __attribute__((address_space(1))) void*)(g), \
                                   (__attribute__((address_space(3))) void*)(l), 16, 0, 0)

// ---------- merged casts: x->fp16 ; w_qkv, w_out -> fp16 transposed ----------
__global__ __launch_bounds__(256) void cast_all(
    const float* __restrict__ x, _Float16* __restrict__ xh,
    const float* __restrict__ w_qkv, _Float16* __restrict__ wqT,
    const float* __restrict__ w_out, _Float16* __restrict__ woT) {
  __shared__ _Float16 hs[64][65];
  const int blk = blockIdx.x;
  const int t = threadIdx.x;

  if (blk < 2048) {
    const int n4 = 8192 * 1024 / 4;
    int i = blk * 256 + t;
    const int stride = 2048 * 256;
    for (; i < n4; i += stride) {
      float4 v = ((const float4*)x)[i];
      f16x4 h;
      h[0] = (_Float16)v.x; h[1] = (_Float16)v.y;
      h[2] = (_Float16)v.z; h[3] = (_Float16)v.w;
      ((f16x4*)xh)[i] = h;
    }
    return;
  }

  const float* in;
  _Float16* hi;
  int R, C, bx, by;
  if (blk < 2048 + 768) {
    const int id = blk - 2048;
    in = w_qkv; hi = wqT; R = 1024; C = 3072;
    bx = id % 48; by = id / 48;
  } else {
    const int id = blk - 2816;
    in = w_out; hi = woT; R = 1024; C = 1024;
    bx = id % 16; by = id / 16;
  }
  const int r0 = by * 64, c0 = bx * 64;
#pragma unroll
  for (int it = 0; it < 4; ++it) {
    int r = (t >> 4) + it * 16;
    int cc = (t & 15) * 4;
    float4 v = *(const float4*)(in + (size_t)(r0 + r) * C + c0 + cc);
    hs[r][cc + 0] = (_Float16)v.x;
    hs[r][cc + 1] = (_Float16)v.y;
    hs[r][cc + 2] = (_Float16)v.z;
    hs[r][cc + 3] = (_Float16)v.w;
  }
  __syncthreads();
  const int oc = t >> 2;
  const int rr = (t & 3) * 16;
#pragma unroll
  for (int g = 0; g < 2; ++g) {
    f16x8 a;
#pragma unroll
    for (int j = 0; j < 8; ++j) a[j] = hs[rr + g * 8 + j][oc];
    *(f16x8*)(hi + (size_t)(c0 + oc) * R + r0 + rr + g * 8) = a;
  }
}

// ---------- GEMM1: qkv = xh @ wqT, 128x128 tile, BK=64, 32x32x16 ----------
__global__ __launch_bounds__(256) void gemm1_qkv(
    const _Float16* __restrict__ Ah, const _Float16* __restrict__ Bh,
    _Float16* __restrict__ qkout, _Float16* __restrict__ vTout) {
  __shared__ char lds[34816];   // staging 2*16384=32768; epilogue 34816
  const int K = 1024;
  const int tid = threadIdx.x;
  const int wave = tid >> 6, lane = tid & 63;
  const int m0 = blockIdx.y * 128, n0 = blockIdx.x * 128;
  const int wr = wave >> 1, wc = wave & 1;
  const int l31 = lane & 31, hi = lane >> 5;

  const int srow_off = lane >> 3;   // 0..7
  const int slot     = lane & 7;

  f32x16 acc[2][2];
#pragma unroll
  for (int mi = 0; mi < 2; ++mi)
#pragma unroll
    for (int ni = 0; ni < 2; ++ni) acc[mi][ni] = (f32x16){0};

  const _Float16* gbase[2];
  gbase[0] = Ah + (size_t)m0 * K;
  gbase[1] = Bh + (size_t)n0 * K;

  for (int k0 = 0; k0 < K; k0 += 64) {
    __syncthreads();
#pragma unroll
    for (int p = 0; p < 2; ++p) {
#pragma unroll
      for (int it = 0; it < 4; ++it) {
        const int rbase = wave * 32 + it * 8;
        const int r  = rbase + srow_off;
        const int gc = slot ^ (r & 7);
        const _Float16* g = gbase[p] + (size_t)r * K + k0 + gc * 8;
        GLOBAL_LOAD_LDS16(g, lds + p * 16384 + rbase * 128);
      }
    }
    __syncthreads();

#pragma unroll
    for (int ks = 0; ks < 4; ++ks) {
      f16x8 af[2], bf[2];
#pragma unroll
      for (int mi = 0; mi < 2; ++mi) {
        const int r = wr * 64 + mi * 32 + l31;
        af[mi] = *(const f16x8*)(lds + 0 * 16384 + r * 128 +
                                 (((2 * ks + hi) ^ (r & 7)) * 16));
      }
#pragma unroll
      for (int ni = 0; ni < 2; ++ni) {
        const int r = wc * 64 + ni * 32 + l31;
        bf[ni] = *(const f16x8*)(lds + 1 * 16384 + r * 128 +
                                 (((2 * ks + hi) ^ (r & 7)) * 16));
      }
#pragma unroll
      for (int mi = 0; mi < 2; ++mi)
#pragma unroll
        for (int ni = 0; ni < 2; ++ni)
          acc[mi][ni] = __builtin_amdgcn_mfma_f32_32x32x16_f16(
              af[mi], bf[ni], acc[mi][ni], 0, 0, 0);
    }
  }

  // epilogue: D row = (reg&3)+8*(reg>>2)+4*hi, col = lane&31 (verified map)
  if (n0 < 2048) {
    const float qsc = (n0 < 1024) ? (float)QK_SCALE : 1.0f;
#pragma unroll
    for (int mi = 0; mi < 2; ++mi)
#pragma unroll
      for (int ni = 0; ni < 2; ++ni) {
        const int col = n0 + wc * 64 + ni * 32 + l31;
#pragma unroll
        for (int reg = 0; reg < 16; ++reg) {
          const int row = m0 + wr * 64 + mi * 32 + (reg & 3) + 8 * (reg >> 2) + 4 * hi;
          qkout[(size_t)row * 2048 + col] = (_Float16)(acc[mi][ni][reg] * qsc);
        }
      }
  } else {
    __syncthreads();
    _Float16* lv = (_Float16*)lds;        // [128 cols][136]
#pragma unroll
    for (int mi = 0; mi < 2; ++mi)
#pragma unroll
      for (int ni = 0; ni < 2; ++ni) {
        const int cc = wc * 64 + ni * 32 + l31;
#pragma unroll
        for (int reg = 0; reg < 16; ++reg) {
          const int r = wr * 64 + mi * 32 + (reg & 3) + 8 * (reg >> 2) + 4 * hi;
          lv[cc * 136 + r] = (_Float16)acc[mi][ni][reg];
        }
      }
    __syncthreads();
    const int bb = m0 >> 10, seq0 = m0 & 1023;
    const int hbase = (n0 - 2048) >> 6;
#pragma unroll
    for (int it = 0; it < 8; ++it) {
      const int idx = tid + it * 256;
      const int cc = idx >> 4, ch = idx & 15;
      f16x8 v = *(const f16x8*)(lv + cc * 136 + ch * 8);
      const int hh = hbase + (cc >> 6), d = cc & 63;
      *(f16x8*)(vTout + (((size_t)bb * 16 + hh) * 64 + d) * 1024 + seq0 + ch * 8) = v;
    }
  }
}

// ---------- MFMA flash attention (counted-vmcnt pipeline, unrolled) ----------
// grid (128, 8): x = h*8+b (XCD-local K/V), y = band. Block = 4 waves;
// wave owns 32 q-rows; KVBLK=64; THREE LDS buffers, depth-2 prefetch.
// Main loop fully unrolled: buffer indices and stage addresses fold to
// compile-time constants (kills the %3 magic-multiplies and per-tile
// 64-bit address rebuilds that inflated VALUBusy).
__global__ __launch_bounds__(256) void attn_mfma(
    const _Float16* __restrict__ qk,   // [8192][2048]
    const _Float16* __restrict__ vT,   // [(b*16+h)*64 + dim][1024]
    _Float16* __restrict__ ao) {       // [8192][1024]
  const int hb   = blockIdx.x;
  const int h    = hb >> 3;
  const int b    = hb & 7;
  const int band = blockIdx.y;
  const int tid  = threadIdx.x;
  const int wave = tid >> 6;
  const int lane = tid & 63;
  const int l31  = lane & 31;
  const int hi   = lane >> 5;
  const int kswz = (l31 & 7) << 4;

  __shared__ _Float16 Ks[3][64 * 64];
  __shared__ _Float16 Vt[3][64 * 64];

  const _Float16* vbase = vT + ((size_t)(b * 16 + h) * 64) * 1024;

  const int qrow_g = b * 1024 + band * 128 + wave * 32 + l31;
  f16x8 qf[4];
#pragma unroll
  for (int c = 0; c < 4; ++c)
    qf[c] = *(const f16x8*)(qk + (size_t)qrow_g * 2048 + h * 64 + c * 16 + hi * 8);

  f16x8 vones;
#pragma unroll
  for (int j = 0; j < 8; ++j) vones[j] = (_Float16)1.0f;

  f32x16 accO0 = {0}, accO1 = {0}, accL = {0};

  const int srow8 = (lane >> 3);
  const int slot  = lane & 7;

  // hoisted per-thread staging bases (tile t adds t*64 rows / t*64 cols)
  const _Float16* gk_base[2];
  const _Float16* gv_base[2];
  int dst_off[2];
#pragma unroll
  for (int it = 0; it < 2; ++it) {
    const int r  = wave * 8 + srow8 + it * 32;
    const int gc = slot ^ (r & 7);
    gk_base[it] = qk + (size_t)(b * 1024 + r) * 2048 + 1024 + h * 64 + gc * 8;
    gv_base[it] = vbase + (size_t)r * 1024 + gc * 8;
    dst_off[it] = (wave * 8 + it * 32) * 128;
  }

  auto stage_t = [&](int t, int buf) {
#pragma unroll
    for (int it = 0; it < 2; ++it) {
      GLOBAL_LOAD_LDS16(gk_base[it] + (size_t)t * (64 * 2048),
                        (char*)&Ks[buf][0] + dst_off[it]);
      GLOBAL_LOAD_LDS16(gv_base[it] + t * 64,
                        (char*)&Vt[buf][0] + dst_off[it]);
    }
  };

  auto compute_tile = [&](const char* ksb, const char* vtb) {
    f32x16 accS0 = {0}, accS1 = {0};
    __builtin_amdgcn_s_setprio(1);
#pragma unroll
    for (int c = 0; c < 4; ++c) {
      f16x8 ka0 = *(const f16x8*)(ksb + l31 * 128 + ((c * 32 + hi * 16) ^ kswz));
      f16x8 ka1 = *(const f16x8*)(ksb + (l31 + 32) * 128 + ((c * 32 + hi * 16) ^ kswz));
      accS0 = __builtin_amdgcn_mfma_f32_32x32x16_f16(ka0, qf[c], accS0, 0, 0, 0);
      accS1 = __builtin_amdgcn_mfma_f32_32x32x16_f16(ka1, qf[c], accS1, 0, 0, 0);
    }
    __builtin_amdgcn_s_setprio(0);

#pragma unroll
    for (int c = 0; c < 4; ++c) {
      float e[8];
#pragma unroll
      for (int k = 0; k < 8; ++k)
        e[k] = __builtin_exp2f((c < 2) ? accS0[(c & 1) * 8 + k]
                                       : accS1[(c & 1) * 8 + k]);
      unsigned q0a = __builtin_bit_cast(unsigned, __builtin_amdgcn_cvt_pkrtz(e[0], e[1]));
      unsigned q0b = __builtin_bit_cast(unsigned, __builtin_amdgcn_cvt_pkrtz(e[2], e[3]));
      unsigned q1a = __builtin_bit_cast(unsigned, __builtin_amdgcn_cvt_pkrtz(e[4], e[5]));
      unsigned q1b = __builtin_bit_cast(unsigned, __builtin_amdgcn_cvt_pkrtz(e[6], e[7]));
      unsigned send_a = hi ? q0a : q1a;
      unsigned send_b = hi ? q0b : q1b;
      unsigned recv_a = __shfl_xor(send_a, 32);
      unsigned recv_b = __shfl_xor(send_b, 32);
      u32x4 pu;
      pu[0] = hi ? recv_a : q0a;
      pu[1] = hi ? recv_b : q0b;
      pu[2] = hi ? q1a : recv_a;
      pu[3] = hi ? q1b : recv_b;
      f16x8 pa = __builtin_bit_cast(f16x8, pu);

      const int kchunk = ((2 * c + hi) * 16) ^ kswz;
      f16x8 vb0 = *(const f16x8*)(vtb + l31 * 128 + kchunk);
      f16x8 vb1 = *(const f16x8*)(vtb + (l31 + 32) * 128 + kchunk);
      __builtin_amdgcn_s_setprio(1);
      accO0 = __builtin_amdgcn_mfma_f32_32x32x16_f16(pa, vb0, accO0, 0, 0, 0);
      accO1 = __builtin_amdgcn_mfma_f32_32x32x16_f16(pa, vb1, accO1, 0, 0, 0);
      accL  = __builtin_amdgcn_mfma_f32_32x32x16_f16(pa, vones, accL, 0, 0, 0);
      __builtin_amdgcn_s_setprio(0);
    }
  };

  stage_t(0, 0);
  stage_t(1, 1);

#pragma unroll
  for (int t = 0; t < 14; ++t) {
    __builtin_amdgcn_s_barrier();                    // A: all done compute(t-1)
    stage_t(t + 2, (t + 2) % 3);                     // consts under unroll
    asm volatile("s_waitcnt vmcnt(8)" ::: "memory"); // drain exactly stage(t)
    __builtin_amdgcn_sched_barrier(0);
    __builtin_amdgcn_s_barrier();                    // B: everyone's stage(t) landed
    const int bt = t % 3;
    compute_tile((const char*)&Ks[bt][0], (const char*)&Vt[bt][0]);
  }
  asm volatile("s_waitcnt vmcnt(4)" ::: "memory");
  __builtin_amdgcn_sched_barrier(0);
  __builtin_amdgcn_s_barrier();
  compute_tile((const char*)&Ks[2][0], (const char*)&Vt[2][0]);   // 14%3=2
  asm volatile("s_waitcnt vmcnt(0)" ::: "memory");
  __builtin_amdgcn_sched_barrier(0);
  __builtin_amdgcn_s_barrier();
  compute_tile((const char*)&Ks[0][0], (const char*)&Vt[0][0]);   // 15%3=0

#pragma unroll
  for (int reg = 0; reg < 16; ++reg) {
    const int qr = (reg & 3) + 8 * (reg >> 2) + 4 * hi;
    const float il = 1.f / accL[reg];
    const size_t grow = (size_t)(b * 1024 + band * 128 + wave * 32 + qr) * 1024 + h * 64;
    ao[grow + l31]      = (_Float16)(accO0[reg] * il);
    ao[grow + 32 + l31] = (_Float16)(accO1[reg] * il);
  }
}

// ---------- GEMM2: out = attn @ woT + bias, BK=64, 32x32x16 ----------
__global__ __launch_bounds__(256) void gemm2_out(
    const _Float16* __restrict__ A,
    const _Float16* __restrict__ B,
    float* __restrict__ C, const float* __restrict__ bias) {
  __shared__ char lds[2 * 16384];
  const int K = 1024;
  const int tid = threadIdx.x;
  const int wave = tid >> 6, lane = tid & 63;
  const int m0 = blockIdx.y * 128, n0 = blockIdx.x * 128;
  const int wr = wave >> 1, wc = wave & 1;
  const int l31 = lane & 31, hi = lane >> 5;

  const int srow_off = lane >> 3;
  const int slot     = lane & 7;

  f32x16 acc[2][2];
#pragma unroll
  for (int mi = 0; mi < 2; ++mi)
#pragma unroll
    for (int ni = 0; ni < 2; ++ni) acc[mi][ni] = (f32x16){0};

  const _Float16* gbase[2];
  gbase[0] = A + (size_t)m0 * K;
  gbase[1] = B + (size_t)n0 * K;

  for (int k0 = 0; k0 < K; k0 += 64) {
    __syncthreads();
#pragma unroll
    for (int p = 0; p < 2; ++p) {
#pragma unroll
      for (int it = 0; it < 4; ++it) {
        const int rbase = wave * 32 + it * 8;
        const int r  = rbase + srow_off;
        const int gc = slot ^ (r & 7);
        const _Float16* g = gbase[p] + (size_t)r * K + k0 + gc * 8;
        GLOBAL_LOAD_LDS16(g, lds + p * 16384 + rbase * 128);
      }
    }
    __syncthreads();

#pragma unroll
    for (int ks = 0; ks < 4; ++ks) {
      f16x8 af[2], bf[2];
#pragma unroll
      for (int mi = 0; mi < 2; ++mi) {
        const int r = wr * 64 + mi * 32 + l31;
        af[mi] = *(const f16x8*)(lds + 0 * 16384 + r * 128 +
                                 (((2 * ks + hi) ^ (r & 7)) * 16));
      }
#pragma unroll
      for (int ni = 0; ni < 2; ++ni) {
        const int r = wc * 64 + ni * 32 + l31;
        bf[ni] = *(const f16x8*)(lds + 1 * 16384 + r * 128 +
                                 (((2 * ks + hi) ^ (r & 7)) * 16));
      }
#pragma unroll
      for (int mi = 0; mi < 2; ++mi)
#pragma unroll
        for (int ni = 0; ni < 2; ++ni)
          acc[mi][ni] = __builtin_amdgcn_mfma_f32_32x32x16_f16(
              af[mi], bf[ni], acc[mi][ni], 0, 0, 0);
    }
  }

#pragma unroll
  for (int mi = 0; mi < 2; ++mi)
#pragma unroll
    for (int ni = 0; ni < 2; ++ni) {
      const int col = n0 + wc * 64 + ni * 32 + l31;
      const float bv = bias[col];
#pragma unroll
      for (int reg = 0; reg < 16; ++reg) {
        const int row = m0 + wr * 64 + mi * 32 + (reg & 3) + 8 * (reg >> 2) + 4 * hi;
        C[(size_t)row * 1024 + col] = acc[mi][ni][reg] + bv;
      }
    }
}

extern "C" void kernel_launch(void* const* d_in, const int* in_sizes, int n_in,
                              void* d_out, int out_size, void* d_ws, size_t ws_size,
                              hipStream_t stream) {
  const float* x     = (const float*)d_in[0];   // [8, 1024, 1024]
  const float* w_qkv = (const float*)d_in[1];   // [1024, 3072]
  const float* w_out = (const float*)d_in[2];   // [1024, 1024]
  const float* b_out = (const float*)d_in[3];   // [1024]
  float* out = (float*)d_out;                   // [8, 1024, 1024]

  char* ws = (char*)d_ws;
  _Float16* xh  = (_Float16*)(ws);
  _Float16* ao  = xh;                           // reused after GEMM1
  _Float16* wqT = (_Float16*)(ws + (32u << 20));
  _Float16* woT = (_Float16*)(ws + (44u << 20));
  _Float16* qkp = (_Float16*)(ws + (48u << 20));
  _Float16* vT  = (_Float16*)(ws + (80u << 20));

  // merged casts (x, w_qkv^T, w_out^T) in one launch
  cast_all<<<3072, 256, 0, stream>>>(x, xh, w_qkv, wqT, w_out, woT);

  // qkv = xh @ wqT  (M=8192, N=3072, K=1024); Q pre-scaled
  gemm1_qkv<<<dim3(24, 64), 256, 0, stream>>>(xh, wqT, qkp, vT);

  // attention: grid x=(h,b) so bands sharing K/V stay on one XCD
  attn_mfma<<<dim3(128, 8), 256, 0, stream>>>(qkp, vT, ao);

  // out = attn @ w_out + b_out (M=8192, N=1024, K=1024) -> f32
  gemm2_out<<<dim3(8, 64), 256, 0, stream>>>(ao, woT, out, b_out);
}

// Round 26
// 169.864 us; speedup vs baseline: 1.0369x; 1.0146x over previous
//
#include <hip/hip_runtime.h>
#include <hip/hip_bf16.h>
#include <math.h>

// B=8, N=1024, DIM=1024, H=16, D_K=64
// Pipeline (all-fp16 MFMA, fp32 accum):
//   merged cast kernel: x -> fp16; w_qkv, w_out -> fp16 transposed [col][k]
//   GEMM1 (BK=64, 32x32x16, DOUBLE-BUFFERED + FULL UNROLL): the 16
//     K-iterations unroll so staged addresses fold into gload_lds
//     immediate offsets (R22's dbuf failed on dynamic-loop VALU; R25
//     proved unroll removes it). Per iter: barrier (drains stage(t),
//     overlapped with compute(t-1)) -> stage(t+1) -> compute(t).
//   flash attention (R25): NO-MAX softmax, MFMA-l, counted-vmcnt
//     3-buffer pipeline, fully unrolled.
//   GEMM2 (same dbuf+unroll template): out = attn @ woT + b_out -> fp32
//
// ws layout (96 MiB):
//   [0,16Mi)   xh [8192][1024] f16   (later reused as attn output plane)
//   [32,38Mi)  wqT [3072][1024] f16
//   [44,46Mi)  woT [1024][1024] f16
//   [48,80Mi)  qk f16 [8192][2048]
//   [80,96Mi)  vT f16 [8*16][64][1024]

typedef __attribute__((ext_vector_type(8))) _Float16 f16x8;
typedef __attribute__((ext_vector_type(4))) _Float16 f16x4;
typedef __attribute__((ext_vector_type(4))) float f32x4;
typedef __attribute__((ext_vector_type(16))) float f32x16;
typedef __attribute__((ext_vector_type(4))) unsigned int u32x4;

#define QK_SCALE 0.18033688011112042f   // 0.125 * log2(e)

#define GLOBAL_LOAD_LDS16(g, l) \
  __builtin_amdgcn_global_load_lds((const __attribute__((address_space(1))) void*)(g), \
                                   (__attribute__((address_space(3))) void*)(l), 16, 0, 0)

// ---------- merged casts: x->fp16 ; w_qkv, w_out -> fp16 transposed ----------
__global__ __launch_bounds__(256) void cast_all(
    const float* __restrict__ x, _Float16* __restrict__ xh,
    const float* __restrict__ w_qkv, _Float16* __restrict__ wqT,
    const float* __restrict__ w_out, _Float16* __restrict__ woT) {
  __shared__ _Float16 hs[64][65];
  const int blk = blockIdx.x;
  const int t = threadIdx.x;

  if (blk < 2048) {
    const int n4 = 8192 * 1024 / 4;
    int i = blk * 256 + t;
    const int stride = 2048 * 256;
    for (; i < n4; i += stride) {
      float4 v = ((const float4*)x)[i];
      f16x4 h;
      h[0] = (_Float16)v.x; h[1] = (_Float16)v.y;
      h[2] = (_Float16)v.z; h[3] = (_Float16)v.w;
      ((f16x4*)xh)[i] = h;
    }
    return;
  }

  const float* in;
  _Float16* hi;
  int R, C, bx, by;
  if (blk < 2048 + 768) {
    const int id = blk - 2048;
    in = w_qkv; hi = wqT; R = 1024; C = 3072;
    bx = id % 48; by = id / 48;
  } else {
    const int id = blk - 2816;
    in = w_out; hi = woT; R = 1024; C = 1024;
    bx = id % 16; by = id / 16;
  }
  const int r0 = by * 64, c0 = bx * 64;
#pragma unroll
  for (int it = 0; it < 4; ++it) {
    int r = (t >> 4) + it * 16;
    int cc = (t & 15) * 4;
    float4 v = *(const float4*)(in + (size_t)(r0 + r) * C + c0 + cc);
    hs[r][cc + 0] = (_Float16)v.x;
    hs[r][cc + 1] = (_Float16)v.y;
    hs[r][cc + 2] = (_Float16)v.z;
    hs[r][cc + 3] = (_Float16)v.w;
  }
  __syncthreads();
  const int oc = t >> 2;
  const int rr = (t & 3) * 16;
#pragma unroll
  for (int g = 0; g < 2; ++g) {
    f16x8 a;
#pragma unroll
    for (int j = 0; j < 8; ++j) a[j] = hs[rr + g * 8 + j][oc];
    *(f16x8*)(hi + (size_t)(c0 + oc) * R + r0 + rr + g * 8) = a;
  }
}

// ---------- GEMM1: qkv = xh @ wqT, 128x128 tile, BK=64, 32x32x16, dbuf ----------
__global__ __launch_bounds__(256) void gemm1_qkv(
    const _Float16* __restrict__ Ah, const _Float16* __restrict__ Bh,
    _Float16* __restrict__ qkout, _Float16* __restrict__ vTout) {
  __shared__ char lds[65536];   // 2 bufs x 2 planes x 16KB; epilogue reuses
  const int K = 1024;
  const int tid = threadIdx.x;
  const int wave = tid >> 6, lane = tid & 63;
  const int m0 = blockIdx.y * 128, n0 = blockIdx.x * 128;
  const int wr = wave >> 1, wc = wave & 1;
  const int l31 = lane & 31, hi = lane >> 5;

  const int srow_off = lane >> 3;   // 0..7
  const int slot     = lane & 7;

  f32x16 acc[2][2];
#pragma unroll
  for (int mi = 0; mi < 2; ++mi)
#pragma unroll
    for (int ni = 0; ni < 2; ++ni) acc[mi][ni] = (f32x16){0};

  const _Float16* gbase[2];
  gbase[0] = Ah + (size_t)m0 * K;
  gbase[1] = Bh + (size_t)n0 * K;

  auto stage_g = [&](int t, int buf) {
#pragma unroll
    for (int p = 0; p < 2; ++p) {
#pragma unroll
      for (int it = 0; it < 4; ++it) {
        const int rbase = wave * 32 + it * 8;
        const int r  = rbase + srow_off;
        const int gc = slot ^ (r & 7);
        const _Float16* g = gbase[p] + (size_t)r * K + t * 64 + gc * 8;
        GLOBAL_LOAD_LDS16(g, lds + buf * 32768 + p * 16384 + rbase * 128);
      }
    }
  };

  auto compute_g = [&](const char* base) {
#pragma unroll
    for (int ks = 0; ks < 4; ++ks) {
      f16x8 af[2], bf[2];
#pragma unroll
      for (int mi = 0; mi < 2; ++mi) {
        const int r = wr * 64 + mi * 32 + l31;
        af[mi] = *(const f16x8*)(base + 0 * 16384 + r * 128 +
                                 (((2 * ks + hi) ^ (r & 7)) * 16));
      }
#pragma unroll
      for (int ni = 0; ni < 2; ++ni) {
        const int r = wc * 64 + ni * 32 + l31;
        bf[ni] = *(const f16x8*)(base + 1 * 16384 + r * 128 +
                                 (((2 * ks + hi) ^ (r & 7)) * 16));
      }
#pragma unroll
      for (int mi = 0; mi < 2; ++mi)
#pragma unroll
        for (int ni = 0; ni < 2; ++ni)
          acc[mi][ni] = __builtin_amdgcn_mfma_f32_32x32x16_f16(
              af[mi], bf[ni], acc[mi][ni], 0, 0, 0);
    }
  };

  stage_g(0, 0);

#pragma unroll
  for (int t = 0; t < 16; ++t) {
    __syncthreads();                         // stage(t) landed (overlapped)
    if (t < 15) stage_g(t + 1, (t + 1) & 1); // prefetch into other buffer
    compute_g(lds + (t & 1) * 32768);
  }

  // epilogue: D row = (reg&3)+8*(reg>>2)+4*hi, col = lane&31 (verified map)
  if (n0 < 2048) {
    const float qsc = (n0 < 1024) ? (float)QK_SCALE : 1.0f;
#pragma unroll
    for (int mi = 0; mi < 2; ++mi)
#pragma unroll
      for (int ni = 0; ni < 2; ++ni) {
        const int col = n0 + wc * 64 + ni * 32 + l31;
#pragma unroll
        for (int reg = 0; reg < 16; ++reg) {
          const int row = m0 + wr * 64 + mi * 32 + (reg & 3) + 8 * (reg >> 2) + 4 * hi;
          qkout[(size_t)row * 2048 + col] = (_Float16)(acc[mi][ni][reg] * qsc);
        }
      }
  } else {
    __syncthreads();
    _Float16* lv = (_Float16*)lds;        // [128 cols][136]
#pragma unroll
    for (int mi = 0; mi < 2; ++mi)
#pragma unroll
      for (int ni = 0; ni < 2; ++ni) {
        const int cc = wc * 64 + ni * 32 + l31;
#pragma unroll
        for (int reg = 0; reg < 16; ++reg) {
          const int r = wr * 64 + mi * 32 + (reg & 3) + 8 * (reg >> 2) + 4 * hi;
          lv[cc * 136 + r] = (_Float16)acc[mi][ni][reg];
        }
      }
    __syncthreads();
    const int bb = m0 >> 10, seq0 = m0 & 1023;
    const int hbase = (n0 - 2048) >> 6;
#pragma unroll
    for (int it = 0; it < 8; ++it) {
      const int idx = tid + it * 256;
      const int cc = idx >> 4, ch = idx & 15;
      f16x8 v = *(const f16x8*)(lv + cc * 136 + ch * 8);
      const int hh = hbase + (cc >> 6), d = cc & 63;
      *(f16x8*)(vTout + (((size_t)bb * 16 + hh) * 64 + d) * 1024 + seq0 + ch * 8) = v;
    }
  }
}

// ---------- MFMA flash attention (counted-vmcnt pipeline, unrolled) ----------
__global__ __launch_bounds__(256) void attn_mfma(
    const _Float16* __restrict__ qk,   // [8192][2048]
    const _Float16* __restrict__ vT,   // [(b*16+h)*64 + dim][1024]
    _Float16* __restrict__ ao) {       // [8192][1024]
  const int hb   = blockIdx.x;
  const int h    = hb >> 3;
  const int b    = hb & 7;
  const int band = blockIdx.y;
  const int tid  = threadIdx.x;
  const int wave = tid >> 6;
  const int lane = tid & 63;
  const int l31  = lane & 31;
  const int hi   = lane >> 5;
  const int kswz = (l31 & 7) << 4;

  __shared__ _Float16 Ks[3][64 * 64];
  __shared__ _Float16 Vt[3][64 * 64];

  const _Float16* vbase = vT + ((size_t)(b * 16 + h) * 64) * 1024;

  const int qrow_g = b * 1024 + band * 128 + wave * 32 + l31;
  f16x8 qf[4];
#pragma unroll
  for (int c = 0; c < 4; ++c)
    qf[c] = *(const f16x8*)(qk + (size_t)qrow_g * 2048 + h * 64 + c * 16 + hi * 8);

  f16x8 vones;
#pragma unroll
  for (int j = 0; j < 8; ++j) vones[j] = (_Float16)1.0f;

  f32x16 accO0 = {0}, accO1 = {0}, accL = {0};

  const int srow8 = (lane >> 3);
  const int slot  = lane & 7;

  const _Float16* gk_base[2];
  const _Float16* gv_base[2];
  int dst_off[2];
#pragma unroll
  for (int it = 0; it < 2; ++it) {
    const int r  = wave * 8 + srow8 + it * 32;
    const int gc = slot ^ (r & 7);
    gk_base[it] = qk + (size_t)(b * 1024 + r) * 2048 + 1024 + h * 64 + gc * 8;
    gv_base[it] = vbase + (size_t)r * 1024 + gc * 8;
    dst_off[it] = (wave * 8 + it * 32) * 128;
  }

  auto stage_t = [&](int t, int buf) {
#pragma unroll
    for (int it = 0; it < 2; ++it) {
      GLOBAL_LOAD_LDS16(gk_base[it] + (size_t)t * (64 * 2048),
                        (char*)&Ks[buf][0] + dst_off[it]);
      GLOBAL_LOAD_LDS16(gv_base[it] + t * 64,
                        (char*)&Vt[buf][0] + dst_off[it]);
    }
  };

  auto compute_tile = [&](const char* ksb, const char* vtb) {
    f32x16 accS0 = {0}, accS1 = {0};
    __builtin_amdgcn_s_setprio(1);
#pragma unroll
    for (int c = 0; c < 4; ++c) {
      f16x8 ka0 = *(const f16x8*)(ksb + l31 * 128 + ((c * 32 + hi * 16) ^ kswz));
      f16x8 ka1 = *(const f16x8*)(ksb + (l31 + 32) * 128 + ((c * 32 + hi * 16) ^ kswz));
      accS0 = __builtin_amdgcn_mfma_f32_32x32x16_f16(ka0, qf[c], accS0, 0, 0, 0);
      accS1 = __builtin_amdgcn_mfma_f32_32x32x16_f16(ka1, qf[c], accS1, 0, 0, 0);
    }
    __builtin_amdgcn_s_setprio(0);

#pragma unroll
    for (int c = 0; c < 4; ++c) {
      float e[8];
#pragma unroll
      for (int k = 0; k < 8; ++k)
        e[k] = __builtin_exp2f((c < 2) ? accS0[(c & 1) * 8 + k]
                                       : accS1[(c & 1) * 8 + k]);
      unsigned q0a = __builtin_bit_cast(unsigned, __builtin_amdgcn_cvt_pkrtz(e[0], e[1]));
      unsigned q0b = __builtin_bit_cast(unsigned, __builtin_amdgcn_cvt_pkrtz(e[2], e[3]));
      unsigned q1a = __builtin_bit_cast(unsigned, __builtin_amdgcn_cvt_pkrtz(e[4], e[5]));
      unsigned q1b = __builtin_bit_cast(unsigned, __builtin_amdgcn_cvt_pkrtz(e[6], e[7]));
      unsigned send_a = hi ? q0a : q1a;
      unsigned send_b = hi ? q0b : q1b;
      unsigned recv_a = __shfl_xor(send_a, 32);
      unsigned recv_b = __shfl_xor(send_b, 32);
      u32x4 pu;
      pu[0] = hi ? recv_a : q0a;
      pu[1] = hi ? recv_b : q0b;
      pu[2] = hi ? q1a : recv_a;
      pu[3] = hi ? q1b : recv_b;
      f16x8 pa = __builtin_bit_cast(f16x8, pu);

      const int kchunk = ((2 * c + hi) * 16) ^ kswz;
      f16x8 vb0 = *(const f16x8*)(vtb + l31 * 128 + kchunk);
      f16x8 vb1 = *(const f16x8*)(vtb + (l31 + 32) * 128 + kchunk);
      __builtin_amdgcn_s_setprio(1);
      accO0 = __builtin_amdgcn_mfma_f32_32x32x16_f16(pa, vb0, accO0, 0, 0, 0);
      accO1 = __builtin_amdgcn_mfma_f32_32x32x16_f16(pa, vb1, accO1, 0, 0, 0);
      accL  = __builtin_amdgcn_mfma_f32_32x32x16_f16(pa, vones, accL, 0, 0, 0);
      __builtin_amdgcn_s_setprio(0);
    }
  };

  stage_t(0, 0);
  stage_t(1, 1);

#pragma unroll
  for (int t = 0; t < 14; ++t) {
    __builtin_amdgcn_s_barrier();                    // A: all done compute(t-1)
    stage_t(t + 2, (t + 2) % 3);                     // consts under unroll
    asm volatile("s_waitcnt vmcnt(8)" ::: "memory"); // drain exactly stage(t)
    __builtin_amdgcn_sched_barrier(0);
    __builtin_amdgcn_s_barrier();                    // B: everyone's stage(t) landed
    const int bt = t % 3;
    compute_tile((const char*)&Ks[bt][0], (const char*)&Vt[bt][0]);
  }
  asm volatile("s_waitcnt vmcnt(4)" ::: "memory");
  __builtin_amdgcn_sched_barrier(0);
  __builtin_amdgcn_s_barrier();
  compute_tile((const char*)&Ks[2][0], (const char*)&Vt[2][0]);   // 14%3=2
  asm volatile("s_waitcnt vmcnt(0)" ::: "memory");
  __builtin_amdgcn_sched_barrier(0);
  __builtin_amdgcn_s_barrier();
  compute_tile((const char*)&Ks[0][0], (const char*)&Vt[0][0]);   // 15%3=0

#pragma unroll
  for (int reg = 0; reg < 16; ++reg) {
    const int qr = (reg & 3) + 8 * (reg >> 2) + 4 * hi;
    const float il = 1.f / accL[reg];
    const size_t grow = (size_t)(b * 1024 + band * 128 + wave * 32 + qr) * 1024 + h * 64;
    ao[grow + l31]      = (_Float16)(accO0[reg] * il);
    ao[grow + 32 + l31] = (_Float16)(accO1[reg] * il);
  }
}

// ---------- GEMM2: out = attn @ woT + bias, BK=64, 32x32x16, dbuf ----------
__global__ __launch_bounds__(256) void gemm2_out(
    const _Float16* __restrict__ A,
    const _Float16* __restrict__ B,
    float* __restrict__ C, const float* __restrict__ bias) {
  __shared__ char lds[65536];
  const int K = 1024;
  const int tid = threadIdx.x;
  const int wave = tid >> 6, lane = tid & 63;
  const int m0 = blockIdx.y * 128, n0 = blockIdx.x * 128;
  const int wr = wave >> 1, wc = wave & 1;
  const int l31 = lane & 31, hi = lane >> 5;

  const int srow_off = lane >> 3;
  const int slot     = lane & 7;

  f32x16 acc[2][2];
#pragma unroll
  for (int mi = 0; mi < 2; ++mi)
#pragma unroll
    for (int ni = 0; ni < 2; ++ni) acc[mi][ni] = (f32x16){0};

  const _Float16* gbase[2];
  gbase[0] = A + (size_t)m0 * K;
  gbase[1] = B + (size_t)n0 * K;

  auto stage_g = [&](int t, int buf) {
#pragma unroll
    for (int p = 0; p < 2; ++p) {
#pragma unroll
      for (int it = 0; it < 4; ++it) {
        const int rbase = wave * 32 + it * 8;
        const int r  = rbase + srow_off;
        const int gc = slot ^ (r & 7);
        const _Float16* g = gbase[p] + (size_t)r * K + t * 64 + gc * 8;
        GLOBAL_LOAD_LDS16(g, lds + buf * 32768 + p * 16384 + rbase * 128);
      }
    }
  };

  auto compute_g = [&](const char* base) {
#pragma unroll
    for (int ks = 0; ks < 4; ++ks) {
      f16x8 af[2], bf[2];
#pragma unroll
      for (int mi = 0; mi < 2; ++mi) {
        const int r = wr * 64 + mi * 32 + l31;
        af[mi] = *(const f16x8*)(base + 0 * 16384 + r * 128 +
                                 (((2 * ks + hi) ^ (r & 7)) * 16));
      }
#pragma unroll
      for (int ni = 0; ni < 2; ++ni) {
        const int r = wc * 64 + ni * 32 + l31;
        bf[ni] = *(const f16x8*)(base + 1 * 16384 + r * 128 +
                                 (((2 * ks + hi) ^ (r & 7)) * 16));
      }
#pragma unroll
      for (int mi = 0; mi < 2; ++mi)
#pragma unroll
        for (int ni = 0; ni < 2; ++ni)
          acc[mi][ni] = __builtin_amdgcn_mfma_f32_32x32x16_f16(
              af[mi], bf[ni], acc[mi][ni], 0, 0, 0);
    }
  };

  stage_g(0, 0);

#pragma unroll
  for (int t = 0; t < 16; ++t) {
    __syncthreads();
    if (t < 15) stage_g(t + 1, (t + 1) & 1);
    compute_g(lds + (t & 1) * 32768);
  }

#pragma unroll
  for (int mi = 0; mi < 2; ++mi)
#pragma unroll
    for (int ni = 0; ni < 2; ++ni) {
      const int col = n0 + wc * 64 + ni * 32 + l31;
      const float bv = bias[col];
#pragma unroll
      for (int reg = 0; reg < 16; ++reg) {
        const int row = m0 + wr * 64 + mi * 32 + (reg & 3) + 8 * (reg >> 2) + 4 * hi;
        C[(size_t)row * 1024 + col] = acc[mi][ni][reg] + bv;
      }
    }
}

extern "C" void kernel_launch(void* const* d_in, const int* in_sizes, int n_in,
                              void* d_out, int out_size, void* d_ws, size_t ws_size,
                              hipStream_t stream) {
  const float* x     = (const float*)d_in[0];   // [8, 1024, 1024]
  const float* w_qkv = (const float*)d_in[1];   // [1024, 3072]
  const float* w_out = (const float*)d_in[2];   // [1024, 1024]
  const float* b_out = (const float*)d_in[3];   // [1024]
  float* out = (float*)d_out;                   // [8, 1024, 1024]

  char* ws = (char*)d_ws;
  _Float16* xh  = (_Float16*)(ws);
  _Float16* ao  = xh;                           // reused after GEMM1
  _Float16* wqT = (_Float16*)(ws + (32u << 20));
  _Float16* woT = (_Float16*)(ws + (44u << 20));
  _Float16* qkp = (_Float16*)(ws + (48u << 20));
  _Float16* vT  = (_Float16*)(ws + (80u << 20));

  // merged casts (x, w_qkv^T, w_out^T) in one launch
  cast_all<<<3072, 256, 0, stream>>>(x, xh, w_qkv, wqT, w_out, woT);

  // qkv = xh @ wqT  (M=8192, N=3072, K=1024); Q pre-scaled
  gemm1_qkv<<<dim3(24, 64), 256, 0, stream>>>(xh, wqT, qkp, vT);

  // attention: grid x=(h,b) so bands sharing K/V stay on one XCD
  attn_mfma<<<dim3(128, 8), 256, 0, stream>>>(qkp, vT, ao);

  // out = attn @ w_out + b_out (M=8192, N=1024, K=1024) -> f32
  gemm2_out<<<dim3(8, 64), 256, 0, stream>>>(ao, woT, out, b_out);
}